// Round 6
// baseline (138.123 us; speedup 1.0000x reference)
//
#include <hip/hip_runtime.h>

// TopologyNetwork: B=1024, N=5000, K=16, 9 levels.
// R19 = R18 resubmitted (container infra failed twice; kernel never ran).
// R18/R19 = R13's rolled-loop structure + 2-node ILP interleave:
//  - Evidence: conflicts -31% (R14/R15) gave dt=0; manual reg pipelining
//    (R17) gave +6us (compiler dropped the prefetch sets, VGPR=40). Nothing
//    saturated (VALU 37%, LDS ~70%, HBM 8%) -> limiter = per-wave serial
//    chain: 16 in-order ds_read returns feeding one serial pk-FMA chain.
//  - Fix: process nodes (n, n+1024) together in one unrolled body: 32
//    independent ds_reads in flight, two independent FMA chains. ~36 extra
//    VGPR, compact body the compiler can schedule freely (no macro pipeline).
//  - Per-edge address math reduced to 1 v_and: pack stores s*8 in low16;
//    read parity folds into the ds_read base (compile-time constant per
//    unrolled level body).
//  - Biases pre-packed f16x2 in k_pack (no per-node cvt in fused).

#define TB 1024
#define TN 5000
#define TK 16
#define TLV 9
#define CPG 4                   // f16 cols per group (8 B per node-row)
#define NG  (TB / CPG)          // 256 col-groups = grid
#define LT  1024                // threads per block (16 waves)
#define PEL (TN * TK)           // u32 per level in packed-edge array

#define PSTRIDE 40448           // bytes per parity (5056 slots x 8 B)

typedef unsigned int u32;
typedef unsigned short u16;
typedef _Float16 h2 __attribute__((ext_vector_type(2)));

__device__ __forceinline__ h2 u2h(u32 v) { return __builtin_bit_cast(h2, v); }
__device__ __forceinline__ u32 h2u(h2 h) { return __builtin_bit_cast(u32, h); }
__device__ __forceinline__ u32 packf(float a, float b) {
    h2 h; h.x = (_Float16)a; h.y = (_Float16)b;
    return h2u(h);
}

// ---- pack: elementwise, fully coalesced ----
// pe[j] = (s*8) | f16(w)<<16 ; b2[l*TN+n] = packf(bias,bias)
__global__ __launch_bounds__(256) void k_pack(
    const int* __restrict__ idx, const float* __restrict__ w,
    const float* __restrict__ biases,
    u32* __restrict__ pe, u32* __restrict__ b2)
{
    const int j = blockIdx.x * 256 + threadIdx.x;
    if (j < TLV * TN * TK) {
        const u32 s = (u32)idx[j];
        h2 hw; hw.x = (_Float16)w[j]; hw.y = (_Float16)0.0f;
        pe[j] = (s * 8u) | (h2u(hw) << 16);
    }
    if (j < TLV * TN) {
        const float b = biases[j];
        b2[j] = packf(b, b);
    }
}

// ---- fused: transpose-in + 9 levels in LDS + transpose-out ----

// one edge for each of the two interleaved nodes (X and Y chains)
#define EDGE2(E0, E1, RP) do {                                                \
    const u32 _o0 = (E0) & 0xffffu;            /* s*8 byte offset */          \
    const u32 _o1 = (E1) & 0xffffu;                                           \
    const uint2 _a = *reinterpret_cast<const uint2*>(lds + (RP) + _o0);       \
    const uint2 _b = *reinterpret_cast<const uint2*>(lds + (RP) + _o1);       \
    asm("v_pk_fma_f16 %0, %1, %2, %0 op_sel:[1,0,0] op_sel_hi:[1,1,1]"        \
        : "+v"(x01) : "v"(E0), "v"(_a.x));                                    \
    asm("v_pk_fma_f16 %0, %1, %2, %0 op_sel:[1,0,0] op_sel_hi:[1,1,1]"        \
        : "+v"(x23) : "v"(E0), "v"(_a.y));                                    \
    asm("v_pk_fma_f16 %0, %1, %2, %0 op_sel:[1,0,0] op_sel_hi:[1,1,1]"        \
        : "+v"(y01) : "v"(E1), "v"(_b.x));                                    \
    asm("v_pk_fma_f16 %0, %1, %2, %0 op_sel:[1,0,0] op_sel_hi:[1,1,1]"        \
        : "+v"(y23) : "v"(E1), "v"(_b.y));                                    \
} while (0)

#define LRELU(acc) do {                                                       \
    h2 _v = u2h(acc);                                                         \
    h2 _t; _t.x = (_Float16)0.1f; _t.y = (_Float16)0.1f;                      \
    _v = __builtin_elementwise_max(_v, _v * _t);                              \
    acc = h2u(_v);                                                            \
} while (0)

// two interleaved nodes: n0 = t + IT*LT, n1 = n0 + LT
#define PAIR(RP, WP, IT) do {                                                 \
    const size_t _n0 = (size_t)(t + (IT) * LT);                               \
    const uint4* _p0 = reinterpret_cast<const uint4*>(ep_l + _n0 * TK);       \
    const uint4* _p1 = reinterpret_cast<const uint4*>(ep_l + (_n0 + LT) * TK);\
    const uint4 A0 = _p0[0], A1 = _p0[1], A2 = _p0[2], A3 = _p0[3];           \
    const uint4 B0 = _p1[0], B1 = _p1[1], B2 = _p1[2], B3 = _p1[3];           \
    u32 x01 = b_l[_n0];      u32 x23 = x01;                                   \
    u32 y01 = b_l[_n0 + LT]; u32 y23 = y01;                                   \
    EDGE2(A0.x, B0.x, RP); EDGE2(A0.y, B0.y, RP);                             \
    EDGE2(A0.z, B0.z, RP); EDGE2(A0.w, B0.w, RP);                             \
    EDGE2(A1.x, B1.x, RP); EDGE2(A1.y, B1.y, RP);                             \
    EDGE2(A1.z, B1.z, RP); EDGE2(A1.w, B1.w, RP);                             \
    EDGE2(A2.x, B2.x, RP); EDGE2(A2.y, B2.y, RP);                             \
    EDGE2(A2.z, B2.z, RP); EDGE2(A2.w, B2.w, RP);                             \
    EDGE2(A3.x, B3.x, RP); EDGE2(A3.y, B3.y, RP);                             \
    EDGE2(A3.z, B3.z, RP); EDGE2(A3.w, B3.w, RP);                             \
    LRELU(x01); LRELU(x23); LRELU(y01); LRELU(y23);                           \
    uint2 _rx; _rx.x = x01; _rx.y = x23;                                      \
    uint2 _ry; _ry.x = y01; _ry.y = y23;                                      \
    *reinterpret_cast<uint2*>(lds + (WP) + (IT) * 8192 + wv) = _rx;           \
    *reinterpret_cast<uint2*>(lds + (WP) + ((IT) + 1) * 8192 + wv) = _ry;     \
} while (0)

// single tail node: n = t + IT*LT (guarded by t4)
#define SINGLE(RP, WP, IT) do {                                               \
    const size_t _n0 = (size_t)(t + (IT) * LT);                               \
    const uint4* _p0 = reinterpret_cast<const uint4*>(ep_l + _n0 * TK);       \
    const uint4 A0 = _p0[0], A1 = _p0[1], A2 = _p0[2], A3 = _p0[3];           \
    u32 x01 = b_l[_n0]; u32 x23 = x01;                                        \
    const u32 es[TK] = {A0.x, A0.y, A0.z, A0.w, A1.x, A1.y, A1.z, A1.w,       \
                        A2.x, A2.y, A2.z, A2.w, A3.x, A3.y, A3.z, A3.w};      \
    _Pragma("unroll")                                                         \
    for (int k = 0; k < TK; ++k) {                                            \
        const u32 _e  = es[k];                                                \
        const u32 _o  = _e & 0xffffu;                                         \
        const uint2 _a = *reinterpret_cast<const uint2*>(lds + (RP) + _o);    \
        asm("v_pk_fma_f16 %0, %1, %2, %0 op_sel:[1,0,0] op_sel_hi:[1,1,1]"    \
            : "+v"(x01) : "v"(_e), "v"(_a.x));                                \
        asm("v_pk_fma_f16 %0, %1, %2, %0 op_sel:[1,0,0] op_sel_hi:[1,1,1]"    \
            : "+v"(x23) : "v"(_e), "v"(_a.y));                                \
    }                                                                         \
    LRELU(x01); LRELU(x23);                                                   \
    uint2 _rx; _rx.x = x01; _rx.y = x23;                                      \
    *reinterpret_cast<uint2*>(lds + (WP) + (IT) * 8192 + wv) = _rx;           \
} while (0)

#define LEVEL(LIDX, RP, WP) do {                                              \
    const u32* ep_l = pe + (size_t)(LIDX) * PEL;                              \
    const u32* b_l  = b2 + (size_t)(LIDX) * TN;                               \
    PAIR(RP, WP, 0);                                                          \
    PAIR(RP, WP, 2);                                                          \
    if (t4) SINGLE(RP, WP, 4);                                                \
    __syncthreads();                                                          \
} while (0)

__global__ __launch_bounds__(LT) void k_fused(
    const float* __restrict__ x,      // [B,N]
    float* __restrict__ out,          // [B,N]
    const u32* __restrict__ pe,       // [LV][TN][TK] (s*8 | f16w<<16)
    const u32* __restrict__ b2)       // [LV][TN] packed f16x2 biases
{
    __shared__ uint2 sbuf[2 * (PSTRIDE / 8)];   // 80,896 B ping-pong
    char* lds = reinterpret_cast<char*>(sbuf);
    const int g = blockIdx.x;
    const int t = threadIdx.x;
    const bool t4 = t < (TN - 4 * LT);          // t < 904
    const u32 wv = (u32)t * 8u;                 // per-thread write offset

    // stage x cols g*4..g*4+3 as f16 rows into parity 0
    {
        const float* xp0 = x + (size_t)(g * CPG + 0) * TN;
        const float* xp1 = x + (size_t)(g * CPG + 1) * TN;
        const float* xp2 = x + (size_t)(g * CPG + 2) * TN;
        const float* xp3 = x + (size_t)(g * CPG + 3) * TN;
        #pragma unroll
        for (int it = 0; it < 4; ++it) {
            const int n = t + it * LT;
            uint2 v;
            v.x = packf(xp0[n], xp1[n]);
            v.y = packf(xp2[n], xp3[n]);
            *reinterpret_cast<uint2*>(lds + it * 8192 + wv) = v;
        }
        if (t4) {
            const int n = t + 4 * LT;
            uint2 v;
            v.x = packf(xp0[n], xp1[n]);
            v.y = packf(xp2[n], xp3[n]);
            *reinterpret_cast<uint2*>(lds + 4 * 8192 + wv) = v;
        }
    }
    __syncthreads();

    // 9 levels; parity (level & 1) is a compile-time constant per body.
    LEVEL(0, 0,       PSTRIDE);
    LEVEL(1, PSTRIDE, 0);
    LEVEL(2, 0,       PSTRIDE);
    LEVEL(3, PSTRIDE, 0);
    LEVEL(4, 0,       PSTRIDE);
    LEVEL(5, PSTRIDE, 0);
    LEVEL(6, 0,       PSTRIDE);
    LEVEL(7, PSTRIDE, 0);
    LEVEL(8, 0,       PSTRIDE);

    // write out cols g*4..g*4+3 (parity 1 holds level-8 results)
    {
        float* op0 = out + (size_t)(g * CPG + 0) * TN;
        float* op1 = out + (size_t)(g * CPG + 1) * TN;
        float* op2 = out + (size_t)(g * CPG + 2) * TN;
        float* op3 = out + (size_t)(g * CPG + 3) * TN;
        #pragma unroll
        for (int it = 0; it < 4; ++it) {
            const int n = t + it * LT;
            const uint2 v =
                *reinterpret_cast<const uint2*>(lds + PSTRIDE + it * 8192 + wv);
            h2 h;
            h = u2h(v.x); op0[n] = (float)h.x; op1[n] = (float)h.y;
            h = u2h(v.y); op2[n] = (float)h.x; op3[n] = (float)h.y;
        }
        if (t4) {
            const int n = t + 4 * LT;
            const uint2 v =
                *reinterpret_cast<const uint2*>(lds + PSTRIDE + 4 * 8192 + wv);
            h2 h;
            h = u2h(v.x); op0[n] = (float)h.x; op1[n] = (float)h.y;
            h = u2h(v.y); op2[n] = (float)h.x; op3[n] = (float)h.y;
        }
    }
}

extern "C" void kernel_launch(void* const* d_in, const int* in_sizes, int n_in,
                              void* d_out, int out_size, void* d_ws, size_t ws_size,
                              hipStream_t stream)
{
    const float* x       = (const float*)d_in[0];   // [B,N]
    const int*   src_idx = (const int*)  d_in[1];   // [LV,N,K]
    const float* weights = (const float*)d_in[2];   // [LV,N,K]
    const float* biases  = (const float*)d_in[3];   // [LV,N]
    float* out = (float*)d_out;                     // [B,N]

    u32* pe = (u32*)d_ws;                           // [LV][TN][TK] = 2.88 MB
    u32* b2 = pe + (size_t)TLV * TN * TK;           // [LV][TN]     = 180 KB

    // pack (elementwise, fully coalesced)
    {
        const int ne = TLV * TN * TK;               // 720000
        hipLaunchKernelGGL(k_pack, dim3((ne + 255) / 256), dim3(256), 0, stream,
                           src_idx, weights, biases, pe, b2);
    }
    // fused 9-level evaluation
    hipLaunchKernelGGL(k_fused, dim3(NG), dim3(LT), 0, stream,
                       x, out, pe, b2);
}